// Round 18
// baseline (200.181 us; speedup 1.0000x reference)
//
#include <hip/hip_runtime.h>
#include <hip/hip_bf16.h>

typedef __bf16 bf16x8 __attribute__((ext_vector_type(8)));
typedef __bf16 bf16x4 __attribute__((ext_vector_type(4)));
typedef float f32x4 __attribute__((ext_vector_type(4)));

#define MFMA_BF16(a, b, c) __builtin_amdgcn_mfma_f32_16x16x32_bf16((a), (b), (c), 0, 0, 0)

__device__ __forceinline__ void g2lds16(void* lds, const void* g) {
  __builtin_amdgcn_global_load_lds(
      (const __attribute__((address_space(1))) void*)g,
      (__attribute__((address_space(3))) void*)lds, 16, 0, 0);
}

enum { EP_BF16 = 0, EP_F32 = 1, EP_ADD_F32 = 2, EP_ADD_BF16OUT = 3 };

// ---------------- generic bf16 GEMM (A,B bf16, g2lds staged) ----------------
// MT=128: 2x2 waves of 64x64. MT=64: 1x4 waves of 64x32. MT=32: 1x4 of 32x32.
// SPLITK: grid.z selects K-chunk [z*1024, ...); bf16 partial to Co+z*2M.
// NBX!=0: XCD-aware bijective block swizzle (requires gridDim.x==NBX, nwg%8==0).
template <int EPI, int MT, bool SPLITK = false, int NBX = 0>
__global__ __launch_bounds__(256, 4) void gemm_nt_kernel(
    const __bf16* __restrict__ A, const __bf16* __restrict__ B, const int K,
    __bf16* __restrict__ Co, float* __restrict__ Cf, const int ldc)
{
  __shared__ __align__(16) __bf16 As[2][MT * 32];
  __shared__ __align__(16) __bf16 Bs[2][128 * 32];
  const int tid = threadIdx.x;
  const int wv = tid >> 6, lane = tid & 63;
  const int r16 = lane & 15, g4 = lane >> 4;
  int bx = blockIdx.x, by = blockIdx.y;
  if constexpr (NBX != 0) {
    const int n = NBX * gridDim.y;
    const int flat = by * NBX + bx;
    const int swz = (flat & 7) * (n >> 3) + (flat >> 3);
    bx = swz % NBX;
    by = swz / NBX;
  }
  const int row0 = by * MT, col0 = bx * 128;
  const int wr = (MT == 128) ? (wv >> 1) * 64 : 0;
  const int wc = (MT == 128) ? (wv & 1) * 64 : wv * 32;
  constexpr int NW = (MT == 128) ? 4 : 2;
  constexpr int MFR = (MT >= 64) ? 4 : 2;
  const int kz0 = SPLITK ? blockIdx.z * 1024 : 0;

  f32x4 acc[MFR][NW];
#pragma unroll
  for (int m = 0; m < MFR; ++m)
#pragma unroll
    for (int n = 0; n < NW; ++n) acc[m][n] = f32x4{0.f, 0.f, 0.f, 0.f};

  auto stage = [&](int buf, int k0) {
    if constexpr (MT == 32) {
      if (tid < 128) {
        const int u = tid, row = u >> 2, cg = ((u & 3) ^ (row & 3)) * 8;
        g2lds16(&As[buf][u * 8], A + (size_t)(row0 + row) * K + k0 + cg);
      }
    } else {
#pragma unroll
      for (int rr = 0; rr < MT / 64; ++rr) {
        const int u = rr * 256 + tid, row = u >> 2, cg = ((u & 3) ^ (row & 3)) * 8;
        g2lds16(&As[buf][u * 8], A + (size_t)(row0 + row) * K + k0 + cg);
      }
    }
#pragma unroll
    for (int rr = 0; rr < 2; ++rr) {
      const int u = rr * 256 + tid, row = u >> 2, cg = ((u & 3) ^ (row & 3)) * 8;
      g2lds16(&Bs[buf][u * 8], B + (size_t)(col0 + row) * K + k0 + cg);
    }
  };

  const int nk = SPLITK ? 32 : (K >> 5);
  const int csw = (g4 ^ (r16 & 3)) * 8;
  int cur = 0;
  stage(0, kz0);
  __syncthreads();

  for (int t = 0; t < nk; ++t) {
    if (t + 1 < nk) stage(cur ^ 1, kz0 + (t + 1) * 32);
    bf16x8 af[MFR], bfr[NW];
#pragma unroll
    for (int m = 0; m < MFR; ++m)
      af[m] = *(const bf16x8*)&As[cur][(wr + m * 16 + r16) * 32 + csw];
#pragma unroll
    for (int n = 0; n < NW; ++n)
      bfr[n] = *(const bf16x8*)&Bs[cur][(wc + n * 16 + r16) * 32 + csw];
#pragma unroll
    for (int m = 0; m < MFR; ++m)
#pragma unroll
      for (int n = 0; n < NW; ++n)
        acc[m][n] = MFMA_BF16(af[m], bfr[n], acc[m][n]);
    __syncthreads();
    cur ^= 1;
  }

  const size_t zoff = SPLITK ? (size_t)blockIdx.z * 2097152 : 0;
  // C/D layout: col = lane&15, row = (lane>>4)*4 + reg
#pragma unroll
  for (int m = 0; m < MFR; ++m)
#pragma unroll
    for (int n = 0; n < NW; ++n)
#pragma unroll
      for (int r = 0; r < 4; ++r) {
        const int row = row0 + wr + m * 16 + g4 * 4 + r;
        const int col = col0 + wc + n * 16 + r16;
        const size_t idx = (size_t)row * ldc + col;
        const float v = acc[m][n][r];
        if constexpr (EPI == EP_BF16) Co[zoff + idx] = (__bf16)v;
        else if constexpr (EPI == EP_F32) __builtin_nontemporal_store(v, &Cf[idx]);
        else if constexpr (EPI == EP_ADD_F32) Cf[idx] += v;
        else Co[idx] = (__bf16)(Cf[idx] + v);
      }
}

// ---- fused rmsnorm2 + gate/up GEMM + silu*mul ----
// ffmid = silu(rms(h)g2 @ Wg^T) * (rms(h)g2 @ Wu^T).  grid (4,128), block 256.
__global__ __launch_bounds__(256, 2) void gemm_gu_rms_kernel(
    const float* __restrict__ h, const float* __restrict__ g2,
    const __bf16* __restrict__ Bg, const __bf16* __restrict__ Bu,
    __bf16* __restrict__ ffmid)
{
  __shared__ __align__(16) __bf16 As[64 * 256];      // 32 KB, resident
  __shared__ __align__(16) __bf16 Bgs[2][128 * 32];
  __shared__ __align__(16) __bf16 Bus[2][128 * 32];
  const int tid = threadIdx.x;
  const int wv = tid >> 6, lane = tid & 63;
  const int r16 = lane & 15, g4 = lane >> 4;
  const int row0 = blockIdx.y * 64, col0 = blockIdx.x * 128;
  const int wc = wv * 32;

  auto stageB = [&](int buf, int k0) {
#pragma unroll
    for (int rr = 0; rr < 2; ++rr) {
      const int u = rr * 256 + tid, row = u >> 2, cg = ((u & 3) ^ (row & 3)) * 8;
      g2lds16(&Bgs[buf][u * 8], Bg + (size_t)(col0 + row) * 256 + k0 + cg);
      g2lds16(&Bus[buf][u * 8], Bu + (size_t)(col0 + row) * 256 + k0 + cg);
    }
  };

  stageB(0, 0);   // overlap B-staging with phase 1

  // Phase 1: rmsnorm rows of h into As.
  {
    const int r = tid >> 2, q = tid & 3;            // row 0..63, col-quarter
    const float* hrow = h + (size_t)(row0 + r) * 256 + q * 64;
    f32x4 hv[16];
    float s = 0.f;
#pragma unroll
    for (int j = 0; j < 16; ++j) {
      hv[j] = *(const f32x4*)(hrow + j * 4);
      s += hv[j][0]*hv[j][0] + hv[j][1]*hv[j][1] + hv[j][2]*hv[j][2] + hv[j][3]*hv[j][3];
    }
    s += __shfl_xor(s, 1);
    s += __shfl_xor(s, 2);
    const float scale = rsqrtf(s * (1.f / 256.f) + 1.1920929e-07f);
#pragma unroll
    for (int cj = 0; cj < 8; ++cj) {
      const int cc = q * 8 + cj;
      const int ccs = cc ^ (r & 15);
      const f32x4 ga = *(const f32x4*)(g2 + q * 64 + cj * 8);
      const f32x4 gb = *(const f32x4*)(g2 + q * 64 + cj * 8 + 4);
      bf16x8 w;
#pragma unroll
      for (int e = 0; e < 4; ++e) {
        w[e]     = (__bf16)(hv[cj * 2][e] * scale * ga[e]);
        w[4 + e] = (__bf16)(hv[cj * 2 + 1][e] * scale * gb[e]);
      }
      *(bf16x8*)&As[r * 256 + ccs * 8] = w;
    }
  }
  __syncthreads();

  f32x4 accG[4][2], accU[4][2];
#pragma unroll
  for (int m = 0; m < 4; ++m)
#pragma unroll
    for (int n = 0; n < 2; ++n) {
      accG[m][n] = f32x4{0.f, 0.f, 0.f, 0.f};
      accU[m][n] = f32x4{0.f, 0.f, 0.f, 0.f};
    }

  const int csw = (g4 ^ (r16 & 3)) * 8;
  int cur = 0;
  for (int t = 0; t < 8; ++t) {
    if (t + 1 < 8) stageB(cur ^ 1, (t + 1) * 32);
    bf16x8 af[4], bg[2], bu[2];
#pragma unroll
    for (int m = 0; m < 4; ++m) {
      const int row = m * 16 + r16;
      const int ccs = (t * 4 + g4) ^ r16;
      af[m] = *(const bf16x8*)&As[row * 256 + ccs * 8];
    }
#pragma unroll
    for (int n = 0; n < 2; ++n) {
      bg[n] = *(const bf16x8*)&Bgs[cur][(wc + n * 16 + r16) * 32 + csw];
      bu[n] = *(const bf16x8*)&Bus[cur][(wc + n * 16 + r16) * 32 + csw];
    }
#pragma unroll
    for (int m = 0; m < 4; ++m)
#pragma unroll
      for (int n = 0; n < 2; ++n) {
        accG[m][n] = MFMA_BF16(af[m], bg[n], accG[m][n]);
        accU[m][n] = MFMA_BF16(af[m], bu[n], accU[m][n]);
      }
    __syncthreads();
    cur ^= 1;
  }

#pragma unroll
  for (int m = 0; m < 4; ++m)
#pragma unroll
    for (int n = 0; n < 2; ++n)
#pragma unroll
      for (int r = 0; r < 4; ++r) {
        const int row = row0 + m * 16 + g4 * 4 + r;
        const int col = col0 + wc + n * 16 + r16;
        const float g = accG[m][n][r];
        const float u = accU[m][n][r];
        ffmid[(size_t)row * 512 + col] = (__bf16)((g / (1.f + __expf(-g))) * u);
      }
}

// ---- Wo GEMM with fused attn-merge A-staging: h += merge(opart) @ Wo^T ----
// grid (2, 256): 32-row x 128-col tiles, K=256 (8 iters: t -> hh=t>>1, half=t&1).
// Merge sums 2 kv-split partials in fixed order (deterministic).
__global__ __launch_bounds__(256, 2) void gemm_wo_kernel(
    const __bf16* __restrict__ opart, const float* __restrict__ lpart,
    const __bf16* __restrict__ B, float* __restrict__ Cf)
{
  __shared__ __align__(16) __bf16 As[2][32 * 32];
  __shared__ __align__(16) __bf16 Bs[2][128 * 32];
  const int tid = threadIdx.x;
  const int wv = tid >> 6, lane = tid & 63;
  const int r16 = lane & 15, g4 = lane >> 4;
  const int row0 = blockIdx.y * 32, col0 = blockIdx.x * 128;
  const int wc = wv * 32;

  f32x4 acc[2][2];
#pragma unroll
  for (int m = 0; m < 2; ++m)
#pragma unroll
    for (int n = 0; n < 2; ++n) acc[m][n] = f32x4{0.f, 0.f, 0.f, 0.f};

  const int arow = tid >> 2;
  const int R = row0 + (arow & 31);
  const int b = R >> 11, rr_ = R & 2047;
  const int qb = rr_ >> 6, rloc = rr_ & 63;
  const int cgrp = ((tid & 3) ^ (arow & 3)) * 8;

  auto stageA = [&](int buf, int t) {
    if (tid < 128) {
      const int hh = t >> 1;
      const int dbase = (t & 1) * 32 + cgrp;
      const size_t pb = ((size_t)((b * 4 + hh) * 32 + qb)) * 2;
      const bf16x8 o0 = *(const bf16x8*)(opart + pb * 4096 + rloc * 64 + dbase);
      const bf16x8 o1 = *(const bf16x8*)(opart + (pb + 1) * 4096 + rloc * 64 + dbase);
      const float inv = 1.f / (lpart[pb * 64 + rloc] + lpart[(pb + 1) * 64 + rloc]);
      bf16x8 w;
#pragma unroll
      for (int j = 0; j < 8; ++j) w[j] = (__bf16)(((float)o0[j] + (float)o1[j]) * inv);
      *(bf16x8*)&As[buf][tid * 8] = w;
    }
  };
  auto stageB = [&](int buf, int k0) {
#pragma unroll
    for (int rr = 0; rr < 2; ++rr) {
      const int u = rr * 256 + tid, row = u >> 2, cg = ((u & 3) ^ (row & 3)) * 8;
      g2lds16(&Bs[buf][u * 8], B + (size_t)(col0 + row) * 256 + k0 + cg);
    }
  };

  const int csw = (g4 ^ (r16 & 3)) * 8;
  int cur = 0;
  stageA(0, 0);
  stageB(0, 0);
  __syncthreads();

  for (int t = 0; t < 8; ++t) {
    if (t + 1 < 8) { stageA(cur ^ 1, t + 1); stageB(cur ^ 1, (t + 1) * 32); }
    bf16x8 af[2], bfr[2];
#pragma unroll
    for (int m = 0; m < 2; ++m)
      af[m] = *(const bf16x8*)&As[cur][(m * 16 + r16) * 32 + csw];
#pragma unroll
    for (int n = 0; n < 2; ++n)
      bfr[n] = *(const bf16x8*)&Bs[cur][(wc + n * 16 + r16) * 32 + csw];
#pragma unroll
    for (int m = 0; m < 2; ++m)
#pragma unroll
      for (int n = 0; n < 2; ++n)
        acc[m][n] = MFMA_BF16(af[m], bfr[n], acc[m][n]);
    __syncthreads();
    cur ^= 1;
  }

#pragma unroll
  for (int m = 0; m < 2; ++m)
#pragma unroll
    for (int n = 0; n < 2; ++n)
#pragma unroll
      for (int r = 0; r < 4; ++r) {
        const int row = row0 + m * 16 + g4 * 4 + r;
        const int col = col0 + wc + n * 16 + r16;
        Cf[(size_t)row * 256 + col] += acc[m][n][r];
      }
}

// fused: h = sum_z bf16 part[z] (4 partials); hn = rmsnorm(h)*g.
__global__ void rmsnorm_reduce_kernel(const __bf16* __restrict__ part, const float* __restrict__ g,
                                      float* __restrict__ h, __bf16* __restrict__ out)
{
  const int wv = threadIdx.x >> 6, lane = threadIdx.x & 63;
  const size_t row = (size_t)blockIdx.x * 4 + wv;
  const size_t i = row * 256 + lane * 4;
  f32x4 v = {0.f, 0.f, 0.f, 0.f};
#pragma unroll
  for (int z = 0; z < 4; ++z) {
    const bf16x4 p = *(const bf16x4*)(part + (size_t)z * 2097152 + i);
#pragma unroll
    for (int j = 0; j < 4; ++j) v[j] += (float)p[j];
  }
  *(f32x4*)(h + i) = v;
  float s = v[0] * v[0] + v[1] * v[1] + v[2] * v[2] + v[3] * v[3];
#pragma unroll
  for (int off = 1; off < 64; off <<= 1) s += __shfl_xor(s, off);
  const float scale = rsqrtf(s * (1.f / 256.f) + 1.1920929e-07f);
  const f32x4 gv = *(const f32x4*)(g + lane * 4);
  bf16x4 o;
#pragma unroll
  for (int j = 0; j < 4; ++j) o[j] = (__bf16)(v[j] * scale * gv[j]);
  *(bf16x4*)(out + i) = o;
}

// single fused fp32->bf16 conversion: x first (94% of threads exit in 1 branch),
// then 7 weight segments.
struct CvtPack { const float* s[8]; __bf16* d[8]; int n[8]; };
__global__ void cvt_all_kernel(CvtPack p)
{
  int i = (blockIdx.x * 256 + threadIdx.x) * 4;
#pragma unroll
  for (int k = 0; k < 8; ++k) {
    if (i < p.n[k]) {
      const f32x4 v = *(const f32x4*)(p.s[k] + i);
      bf16x4 o;
#pragma unroll
      for (int j = 0; j < 4; ++j) o[j] = (__bf16)v[j];
      *(bf16x4*)(p.d[k] + i) = o;
      return;
    }
    i -= p.n[k];
  }
}

// Flash attention: no-max softmax (p=exp(s/8), additive partials), kv-split x2,
// balanced qb pairing, swizzled conflict-free LDS. O-partials in bf16.
// grid (16 bh, 32 ycode, 2 z), block 256 (4 waves x 16 q-rows).
__global__ __launch_bounds__(256, 4) void attn_kernel(
    const __bf16* __restrict__ qkv, __bf16* __restrict__ opart, float* __restrict__ lpart)
{
  const int bh = blockIdx.x;
  const int by = blockIdx.y;
  const int qb = (by < 16) ? (31 - by) : (by - 16);
  const int z = blockIdx.z;
  const int b = bh >> 2, hh = bh & 3;
  const int tid = threadIdx.x, wv = tid >> 6, lane = tid & 63;
  const int r16 = lane & 15, g4 = lane >> 4;
  const __bf16* base = qkv + (size_t)b * 2048 * 768;
  const int q0 = qb * 64;

  __shared__ __align__(16) __bf16 Ks[2][64 * 64];
  __shared__ __align__(16) __bf16 Vt[64 * 72];
  __shared__ __align__(16) __bf16 Ps[4][16 * 72];

  bf16x8 qf[2];
  {
    const __bf16* qrow = base + (size_t)(q0 + wv * 16 + r16) * 768 + hh * 64;
    qf[0] = *(const bf16x8*)(qrow + g4 * 8);
    qf[1] = *(const bf16x8*)(qrow + 32 + g4 * 8);
  }

  f32x4 oacc[4];
#pragma unroll
  for (int t = 0; t < 4; ++t) oacc[t] = f32x4{0.f, 0.f, 0.f, 0.f};
  float lsum[4] = {0.f, 0.f, 0.f, 0.f};

  auto stageK = [&](int buf, int kv0) {
#pragma unroll
    for (int rr = 0; rr < 2; ++rr) {
      const int u = rr * 256 + tid;
      const int kv = u >> 3, c = u & 7;
      g2lds16(&Ks[buf][u * 8],
              base + (size_t)(kv0 + kv) * 768 + 256 + hh * 64 + ((c ^ (kv & 7)) * 8));
    }
  };
  const int vrow = tid >> 2, vdg = (tid & 3) * 16;
  const int va_ = vrow >> 3, vb_ = vrow & 7;

  bf16x8 v0r, v1r;
  auto loadV = [&](int kv0) {
    const __bf16* vsrc = base + (size_t)(kv0 + vrow) * 768 + 512 + hh * 64 + vdg;
    v0r = *(const bf16x8*)vsrc;
    v1r = *(const bf16x8*)(vsrc + 8);
  };
  auto writeVt = [&]() {
#pragma unroll
    for (int i = 0; i < 8; ++i) {
      int d = vdg + i;
      Vt[d * 72 + ((va_ ^ (d >> 3)) << 3) + vb_] = v0r[i];
      d = vdg + 8 + i;
      Vt[d * 72 + ((va_ ^ (d >> 3)) << 3) + vb_] = v1r[i];
    }
  };

  int c = z, cur = 0;
  const bool any = (c <= qb);
  if (any) { stageK(0, c * 64); loadV(c * 64); }
  __syncthreads();
  if (any) writeVt();
  __syncthreads();

  while (c <= qb) {
    const int nxt = c + 2;
    if (nxt <= qb) { stageK(cur ^ 1, nxt * 64); loadV(nxt * 64); }

    f32x4 sacc[4];
#pragma unroll
    for (int t = 0; t < 4; ++t) sacc[t] = f32x4{0.f, 0.f, 0.f, 0.f};
#pragma unroll
    for (int t = 0; t < 4; ++t)
#pragma unroll
      for (int kk = 0; kk < 2; ++kk) {
        const bf16x8 kf = *(const bf16x8*)
            &Ks[cur][(t * 16 + r16) * 64 + (((kk * 4 + g4) ^ (r16 & 7)) * 8)];
        sacc[t] = MFMA_BF16(qf[kk], kf, sacc[t]);
      }

    const bool diag = (c == qb);
#pragma unroll
    for (int t = 0; t < 4; ++t)
#pragma unroll
      for (int r = 0; r < 4; ++r) {
        float p = __expf(sacc[t][r] * 0.125f);
        if (diag && (t * 16 + r16 > wv * 16 + g4 * 4 + r)) p = 0.f;
        lsum[r] += p;
        Ps[wv][(g4 * 4 + r) * 72 + t * 16 + r16] = (__bf16)p;
      }
    bf16x8 pa[2];
    pa[0] = *(const bf16x8*)&Ps[wv][r16 * 72 + g4 * 8];
    pa[1] = *(const bf16x8*)&Ps[wv][r16 * 72 + 32 + g4 * 8];

#pragma unroll
    for (int t2 = 0; t2 < 4; ++t2)
#pragma unroll
      for (int kk = 0; kk < 2; ++kk) {
        const int d = t2 * 16 + r16;
        const bf16x8 vf = *(const bf16x8*)
            &Vt[d * 72 + (((kk * 4 + g4) ^ (d >> 3)) * 8)];
        oacc[t2] = MFMA_BF16(pa[kk], vf, oacc[t2]);
      }

    __syncthreads();
    if (nxt <= qb) writeVt();
    __syncthreads();
    c = nxt;
    cur ^= 1;
  }

#pragma unroll
  for (int r = 0; r < 4; ++r) {
    lsum[r] += __shfl_xor(lsum[r], 1);
    lsum[r] += __shfl_xor(lsum[r], 2);
    lsum[r] += __shfl_xor(lsum[r], 4);
    lsum[r] += __shfl_xor(lsum[r], 8);
  }
  const size_t pb = (size_t)(bh * 32 + qb) * 2 + z;
  __bf16* op = opart + pb * 4096;
#pragma unroll
  for (int t2 = 0; t2 < 4; ++t2)
#pragma unroll
    for (int r = 0; r < 4; ++r)
      op[(wv * 16 + g4 * 4 + r) * 64 + t2 * 16 + r16] = (__bf16)oacc[t2][r];
  if (r16 == 0) {
    float* lp = lpart + pb * 64;
#pragma unroll
    for (int r = 0; r < 4; ++r) lp[wv * 16 + g4 * 4 + r] = lsum[r];
  }
}

extern "C" void kernel_launch(void* const* d_in, const int* in_sizes, int n_in,
                              void* d_out, int out_size, void* d_ws, size_t ws_size,
                              hipStream_t stream) {
  (void)in_sizes; (void)n_in; (void)out_size; (void)ws_size;
  const float* x     = (const float*)d_in[0];
  const float* Wdown = (const float*)d_in[1];
  const float* Wup   = (const float*)d_in[2];
  const float* Wqkv  = (const float*)d_in[3];
  const float* Wo    = (const float*)d_in[4];
  const float* Wgate = (const float*)d_in[5];
  const float* Wupff = (const float*)d_in[6];
  const float* Wdff  = (const float*)d_in[7];
  const float* g1    = (const float*)d_in[8];
  const float* g2    = (const float*)d_in[9];
  float* out = (float*)d_out;   // output is fp32 (verified R5)

  const size_t MB = 1 << 20;
  char* ws = (char*)d_ws;
  float*  h  = (float*)ws;                            // [0, 8M)
  __bf16* hn = (__bf16*)(ws + 8 * MB);                // [8M, 12M)
  __bf16* hb = (__bf16*)(ws + 12 * MB);               // [12M, 16M)
  __bf16* wb_down = (__bf16*)(ws + 16 * MB);
  __bf16* wb_up   = (__bf16*)(ws + 18 * MB);
  __bf16* wb_qkv  = (__bf16*)(ws + 20 * MB);
  __bf16* wb_o    = (__bf16*)(ws + 20 * MB + 384 * 1024);
  __bf16* wb_gate = (__bf16*)(ws + 20 * MB + 512 * 1024);
  __bf16* wb_upff = (__bf16*)(ws + 20 * MB + 768 * 1024);
  __bf16* wb_dff  = (__bf16*)(ws + 21 * MB);

  // d_out (128 MiB) doubles as scratch. Lifetimes (all dead before final GEMM):
  //   xb    [0,64M)    cvt -> gemm1
  //   hpart [64,80M)   gemm1 -> rmsnorm_reduce (4 x 4MB bf16)
  //   qkv   [0,12M)    qkv-gemm -> attn          (xb dead)
  //   ffmid [12,20M)   gu_rms-gemm -> dff-gemm
  //   opart [36,44.4M) attn -> wo-gemm (bf16, 2 kv-split partials)
  //   lpart [53,53.25M)
  char* ob = (char*)d_out;
  __bf16* xb    = (__bf16*)(ob);
  __bf16* hpart = (__bf16*)(ob + 64 * MB);
  __bf16* qkv   = (__bf16*)(ob);
  __bf16* ffmid = (__bf16*)(ob + 12 * MB);
  __bf16* opart = (__bf16*)(ob + 36 * MB);
  float* lpart  = (float*)(ob + 53 * MB);

  CvtPack cp;
  cp.s[0] = x;     cp.d[0] = xb;      cp.n[0] = 33554432;
  cp.s[1] = Wdown; cp.d[1] = wb_down; cp.n[1] = 1048576;
  cp.s[2] = Wup;   cp.d[2] = wb_up;   cp.n[2] = 1048576;
  cp.s[3] = Wqkv;  cp.d[3] = wb_qkv;  cp.n[3] = 196608;
  cp.s[4] = Wo;    cp.d[4] = wb_o;    cp.n[4] = 65536;
  cp.s[5] = Wgate; cp.d[5] = wb_gate; cp.n[5] = 131072;
  cp.s[6] = Wupff; cp.d[6] = wb_upff; cp.n[6] = 131072;
  cp.s[7] = Wdff;  cp.d[7] = wb_dff;  cp.n[7] = 131072;
  cvt_all_kernel<<<35456, 256, 0, stream>>>(cp);

  // h_part = xb @ Wdown^T : bf16 template, split-K x4 (512 blocks = 2/CU).
  gemm_nt_kernel<EP_BF16, 128, true><<<dim3(2, 64, 4), 256, 0, stream>>>(
      xb, wb_down, 4096, hpart, nullptr, 256);
  // h = sum 4 partials; hn = rmsnorm(h)*g1  (fused)
  rmsnorm_reduce_kernel<<<2048, 256, 0, stream>>>(hpart, g1, h, hn);

  gemm_nt_kernel<EP_BF16, 64><<<dim3(6, 128), 256, 0, stream>>>(
      hn, wb_qkv, 256, qkv, nullptr, 768);
  attn_kernel<<<dim3(16, 32, 2), 256, 0, stream>>>(qkv, opart, lpart);
  // h += merge(opart,lpart) @ Wo^T  (2-way merge fused into A-staging)
  gemm_wo_kernel<<<dim3(2, 256), 256, 0, stream>>>(opart, lpart, wb_o, h);
  // ffmid = silu(rms(h)g2 @ Wgate^T) * (rms(h)g2 @ Wupff^T)  (rmsnorm fused)
  gemm_gu_rms_kernel<<<dim3(4, 128), 256, 0, stream>>>(h, g2, wb_gate, wb_upff, ffmid);
  // h += ffmid @ Wdff^T ; hb = bf16(h)   (32-row tiles, 512 blocks)
  gemm_nt_kernel<EP_ADD_BF16OUT, 32><<<dim3(2, 256), 256, 0, stream>>>(
      ffmid, wb_dff, 512, hb, h, 256);
  // out = hb @ Wup^T  -> fp32 NT stores, XCD-swizzled blocks (T1)
  gemm_nt_kernel<EP_F32, 128, false, 32><<<dim3(32, 64), 256, 0, stream>>>(
      hb, wb_up, 256, nullptr, out, 4096);
}

// Round 19
// 196.427 us; speedup vs baseline: 1.0191x; 1.0191x over previous
//
#include <hip/hip_runtime.h>
#include <hip/hip_bf16.h>

typedef __bf16 bf16x8 __attribute__((ext_vector_type(8)));
typedef __bf16 bf16x4 __attribute__((ext_vector_type(4)));
typedef float f32x4 __attribute__((ext_vector_type(4)));

#define MFMA_BF16(a, b, c) __builtin_amdgcn_mfma_f32_16x16x32_bf16((a), (b), (c), 0, 0, 0)

__device__ __forceinline__ void g2lds16(void* lds, const void* g) {
  __builtin_amdgcn_global_load_lds(
      (const __attribute__((address_space(1))) void*)g,
      (__attribute__((address_space(3))) void*)lds, 16, 0, 0);
}

enum { EP_BF16 = 0, EP_F32 = 1, EP_ADD_F32 = 2, EP_ADD_BF16OUT = 3 };

// ---------------- generic bf16 GEMM (A,B bf16, g2lds staged) ----------------
// MT=128: 2x2 waves of 64x64. MT=64: 1x4 waves of 64x32. MT=32: 1x4 of 32x32.
// SPLITK: grid.z selects K-chunk [z*1024, ...); bf16 partial to Co+z*2M.
template <int EPI, int MT, bool SPLITK = false>
__global__ __launch_bounds__(256, 4) void gemm_nt_kernel(
    const __bf16* __restrict__ A, const __bf16* __restrict__ B, const int K,
    __bf16* __restrict__ Co, float* __restrict__ Cf, const int ldc)
{
  __shared__ __align__(16) __bf16 As[2][MT * 32];
  __shared__ __align__(16) __bf16 Bs[2][128 * 32];
  const int tid = threadIdx.x;
  const int wv = tid >> 6, lane = tid & 63;
  const int r16 = lane & 15, g4 = lane >> 4;
  const int row0 = blockIdx.y * MT, col0 = blockIdx.x * 128;
  const int wr = (MT == 128) ? (wv >> 1) * 64 : 0;
  const int wc = (MT == 128) ? (wv & 1) * 64 : wv * 32;
  constexpr int NW = (MT == 128) ? 4 : 2;
  constexpr int MFR = (MT >= 64) ? 4 : 2;
  const int kz0 = SPLITK ? blockIdx.z * 1024 : 0;

  f32x4 acc[MFR][NW];
#pragma unroll
  for (int m = 0; m < MFR; ++m)
#pragma unroll
    for (int n = 0; n < NW; ++n) acc[m][n] = f32x4{0.f, 0.f, 0.f, 0.f};

  auto stage = [&](int buf, int k0) {
    if constexpr (MT == 32) {
      if (tid < 128) {
        const int u = tid, row = u >> 2, cg = ((u & 3) ^ (row & 3)) * 8;
        g2lds16(&As[buf][u * 8], A + (size_t)(row0 + row) * K + k0 + cg);
      }
    } else {
#pragma unroll
      for (int rr = 0; rr < MT / 64; ++rr) {
        const int u = rr * 256 + tid, row = u >> 2, cg = ((u & 3) ^ (row & 3)) * 8;
        g2lds16(&As[buf][u * 8], A + (size_t)(row0 + row) * K + k0 + cg);
      }
    }
#pragma unroll
    for (int rr = 0; rr < 2; ++rr) {
      const int u = rr * 256 + tid, row = u >> 2, cg = ((u & 3) ^ (row & 3)) * 8;
      g2lds16(&Bs[buf][u * 8], B + (size_t)(col0 + row) * K + k0 + cg);
    }
  };

  const int nk = SPLITK ? 32 : (K >> 5);
  const int csw = (g4 ^ (r16 & 3)) * 8;
  int cur = 0;
  stage(0, kz0);
  __syncthreads();

  for (int t = 0; t < nk; ++t) {
    if (t + 1 < nk) stage(cur ^ 1, kz0 + (t + 1) * 32);
    bf16x8 af[MFR], bfr[NW];
#pragma unroll
    for (int m = 0; m < MFR; ++m)
      af[m] = *(const bf16x8*)&As[cur][(wr + m * 16 + r16) * 32 + csw];
#pragma unroll
    for (int n = 0; n < NW; ++n)
      bfr[n] = *(const bf16x8*)&Bs[cur][(wc + n * 16 + r16) * 32 + csw];
#pragma unroll
    for (int m = 0; m < MFR; ++m)
#pragma unroll
      for (int n = 0; n < NW; ++n)
        acc[m][n] = MFMA_BF16(af[m], bfr[n], acc[m][n]);
    __syncthreads();
    cur ^= 1;
  }

  const size_t zoff = SPLITK ? (size_t)blockIdx.z * 2097152 : 0;
  // C/D layout: col = lane&15, row = (lane>>4)*4 + reg
#pragma unroll
  for (int m = 0; m < MFR; ++m)
#pragma unroll
    for (int n = 0; n < NW; ++n)
#pragma unroll
      for (int r = 0; r < 4; ++r) {
        const int row = row0 + wr + m * 16 + g4 * 4 + r;
        const int col = col0 + wc + n * 16 + r16;
        const size_t idx = (size_t)row * ldc + col;
        const float v = acc[m][n][r];
        if constexpr (EPI == EP_BF16) Co[zoff + idx] = (__bf16)v;
        else if constexpr (EPI == EP_F32) __builtin_nontemporal_store(v, &Cf[idx]);
        else if constexpr (EPI == EP_ADD_F32) Cf[idx] += v;
        else Co[idx] = (__bf16)(Cf[idx] + v);
      }
}

// ---- fused rmsnorm2 + gate/up GEMM + silu*mul ----
// ffmid = silu(rms(h)g2 @ Wg^T) * (rms(h)g2 @ Wu^T).  grid (4,128), block 256.
__global__ __launch_bounds__(256, 2) void gemm_gu_rms_kernel(
    const float* __restrict__ h, const float* __restrict__ g2,
    const __bf16* __restrict__ Bg, const __bf16* __restrict__ Bu,
    __bf16* __restrict__ ffmid)
{
  __shared__ __align__(16) __bf16 As[64 * 256];      // 32 KB, resident
  __shared__ __align__(16) __bf16 Bgs[2][128 * 32];
  __shared__ __align__(16) __bf16 Bus[2][128 * 32];
  const int tid = threadIdx.x;
  const int wv = tid >> 6, lane = tid & 63;
  const int r16 = lane & 15, g4 = lane >> 4;
  const int row0 = blockIdx.y * 64, col0 = blockIdx.x * 128;
  const int wc = wv * 32;

  auto stageB = [&](int buf, int k0) {
#pragma unroll
    for (int rr = 0; rr < 2; ++rr) {
      const int u = rr * 256 + tid, row = u >> 2, cg = ((u & 3) ^ (row & 3)) * 8;
      g2lds16(&Bgs[buf][u * 8], Bg + (size_t)(col0 + row) * 256 + k0 + cg);
      g2lds16(&Bus[buf][u * 8], Bu + (size_t)(col0 + row) * 256 + k0 + cg);
    }
  };

  stageB(0, 0);   // overlap B-staging with phase 1

  // Phase 1: rmsnorm rows of h into As.
  {
    const int r = tid >> 2, q = tid & 3;            // row 0..63, col-quarter
    const float* hrow = h + (size_t)(row0 + r) * 256 + q * 64;
    f32x4 hv[16];
    float s = 0.f;
#pragma unroll
    for (int j = 0; j < 16; ++j) {
      hv[j] = *(const f32x4*)(hrow + j * 4);
      s += hv[j][0]*hv[j][0] + hv[j][1]*hv[j][1] + hv[j][2]*hv[j][2] + hv[j][3]*hv[j][3];
    }
    s += __shfl_xor(s, 1);
    s += __shfl_xor(s, 2);
    const float scale = rsqrtf(s * (1.f / 256.f) + 1.1920929e-07f);
#pragma unroll
    for (int cj = 0; cj < 8; ++cj) {
      const int cc = q * 8 + cj;
      const int ccs = cc ^ (r & 15);
      const f32x4 ga = *(const f32x4*)(g2 + q * 64 + cj * 8);
      const f32x4 gb = *(const f32x4*)(g2 + q * 64 + cj * 8 + 4);
      bf16x8 w;
#pragma unroll
      for (int e = 0; e < 4; ++e) {
        w[e]     = (__bf16)(hv[cj * 2][e] * scale * ga[e]);
        w[4 + e] = (__bf16)(hv[cj * 2 + 1][e] * scale * gb[e]);
      }
      *(bf16x8*)&As[r * 256 + ccs * 8] = w;
    }
  }
  __syncthreads();

  f32x4 accG[4][2], accU[4][2];
#pragma unroll
  for (int m = 0; m < 4; ++m)
#pragma unroll
    for (int n = 0; n < 2; ++n) {
      accG[m][n] = f32x4{0.f, 0.f, 0.f, 0.f};
      accU[m][n] = f32x4{0.f, 0.f, 0.f, 0.f};
    }

  const int csw = (g4 ^ (r16 & 3)) * 8;
  int cur = 0;
  for (int t = 0; t < 8; ++t) {
    if (t + 1 < 8) stageB(cur ^ 1, (t + 1) * 32);
    bf16x8 af[4], bg[2], bu[2];
#pragma unroll
    for (int m = 0; m < 4; ++m) {
      const int row = m * 16 + r16;
      const int ccs = (t * 4 + g4) ^ r16;
      af[m] = *(const bf16x8*)&As[row * 256 + ccs * 8];
    }
#pragma unroll
    for (int n = 0; n < 2; ++n) {
      bg[n] = *(const bf16x8*)&Bgs[cur][(wc + n * 16 + r16) * 32 + csw];
      bu[n] = *(const bf16x8*)&Bus[cur][(wc + n * 16 + r16) * 32 + csw];
    }
#pragma unroll
    for (int m = 0; m < 4; ++m)
#pragma unroll
      for (int n = 0; n < 2; ++n) {
        accG[m][n] = MFMA_BF16(af[m], bg[n], accG[m][n]);
        accU[m][n] = MFMA_BF16(af[m], bu[n], accU[m][n]);
      }
    __syncthreads();
    cur ^= 1;
  }

#pragma unroll
  for (int m = 0; m < 4; ++m)
#pragma unroll
    for (int n = 0; n < 2; ++n)
#pragma unroll
      for (int r = 0; r < 4; ++r) {
        const int row = row0 + m * 16 + g4 * 4 + r;
        const int col = col0 + wc + n * 16 + r16;
        const float g = accG[m][n][r];
        const float u = accU[m][n][r];
        ffmid[(size_t)row * 512 + col] = (__bf16)((g / (1.f + __expf(-g))) * u);
      }
}

// ---- Wo GEMM with fused attn-merge A-staging: h += merge(opart) @ Wo^T ----
// grid (2, 256): 32-row x 128-col tiles, K=256 (8 iters: t -> hh=t>>1, half=t&1).
// Merge sums 2 kv-split partials in fixed order (deterministic).
__global__ __launch_bounds__(256, 2) void gemm_wo_kernel(
    const __bf16* __restrict__ opart, const float* __restrict__ lpart,
    const __bf16* __restrict__ B, float* __restrict__ Cf)
{
  __shared__ __align__(16) __bf16 As[2][32 * 32];
  __shared__ __align__(16) __bf16 Bs[2][128 * 32];
  const int tid = threadIdx.x;
  const int wv = tid >> 6, lane = tid & 63;
  const int r16 = lane & 15, g4 = lane >> 4;
  const int row0 = blockIdx.y * 32, col0 = blockIdx.x * 128;
  const int wc = wv * 32;

  f32x4 acc[2][2];
#pragma unroll
  for (int m = 0; m < 2; ++m)
#pragma unroll
    for (int n = 0; n < 2; ++n) acc[m][n] = f32x4{0.f, 0.f, 0.f, 0.f};

  const int arow = tid >> 2;
  const int R = row0 + (arow & 31);
  const int b = R >> 11, rr_ = R & 2047;
  const int qb = rr_ >> 6, rloc = rr_ & 63;
  const int cgrp = ((tid & 3) ^ (arow & 3)) * 8;

  auto stageA = [&](int buf, int t) {
    if (tid < 128) {
      const int hh = t >> 1;
      const int dbase = (t & 1) * 32 + cgrp;
      const size_t pb = ((size_t)((b * 4 + hh) * 32 + qb)) * 2;
      const bf16x8 o0 = *(const bf16x8*)(opart + pb * 4096 + rloc * 64 + dbase);
      const bf16x8 o1 = *(const bf16x8*)(opart + (pb + 1) * 4096 + rloc * 64 + dbase);
      const float inv = 1.f / (lpart[pb * 64 + rloc] + lpart[(pb + 1) * 64 + rloc]);
      bf16x8 w;
#pragma unroll
      for (int j = 0; j < 8; ++j) w[j] = (__bf16)(((float)o0[j] + (float)o1[j]) * inv);
      *(bf16x8*)&As[buf][tid * 8] = w;
    }
  };
  auto stageB = [&](int buf, int k0) {
#pragma unroll
    for (int rr = 0; rr < 2; ++rr) {
      const int u = rr * 256 + tid, row = u >> 2, cg = ((u & 3) ^ (row & 3)) * 8;
      g2lds16(&Bs[buf][u * 8], B + (size_t)(col0 + row) * 256 + k0 + cg);
    }
  };

  const int csw = (g4 ^ (r16 & 3)) * 8;
  int cur = 0;
  stageA(0, 0);
  stageB(0, 0);
  __syncthreads();

  for (int t = 0; t < 8; ++t) {
    if (t + 1 < 8) { stageA(cur ^ 1, t + 1); stageB(cur ^ 1, (t + 1) * 32); }
    bf16x8 af[2], bfr[2];
#pragma unroll
    for (int m = 0; m < 2; ++m)
      af[m] = *(const bf16x8*)&As[cur][(m * 16 + r16) * 32 + csw];
#pragma unroll
    for (int n = 0; n < 2; ++n)
      bfr[n] = *(const bf16x8*)&Bs[cur][(wc + n * 16 + r16) * 32 + csw];
#pragma unroll
    for (int m = 0; m < 2; ++m)
#pragma unroll
      for (int n = 0; n < 2; ++n)
        acc[m][n] = MFMA_BF16(af[m], bfr[n], acc[m][n]);
    __syncthreads();
    cur ^= 1;
  }

#pragma unroll
  for (int m = 0; m < 2; ++m)
#pragma unroll
    for (int n = 0; n < 2; ++n)
#pragma unroll
      for (int r = 0; r < 4; ++r) {
        const int row = row0 + m * 16 + g4 * 4 + r;
        const int col = col0 + wc + n * 16 + r16;
        Cf[(size_t)row * 256 + col] += acc[m][n][r];
      }
}

// fused: h = sum_z bf16 part[z] (4 partials); hn = rmsnorm(h)*g.
__global__ void rmsnorm_reduce_kernel(const __bf16* __restrict__ part, const float* __restrict__ g,
                                      float* __restrict__ h, __bf16* __restrict__ out)
{
  const int wv = threadIdx.x >> 6, lane = threadIdx.x & 63;
  const size_t row = (size_t)blockIdx.x * 4 + wv;
  const size_t i = row * 256 + lane * 4;
  f32x4 v = {0.f, 0.f, 0.f, 0.f};
#pragma unroll
  for (int z = 0; z < 4; ++z) {
    const bf16x4 p = *(const bf16x4*)(part + (size_t)z * 2097152 + i);
#pragma unroll
    for (int j = 0; j < 4; ++j) v[j] += (float)p[j];
  }
  *(f32x4*)(h + i) = v;
  float s = v[0] * v[0] + v[1] * v[1] + v[2] * v[2] + v[3] * v[3];
#pragma unroll
  for (int off = 1; off < 64; off <<= 1) s += __shfl_xor(s, off);
  const float scale = rsqrtf(s * (1.f / 256.f) + 1.1920929e-07f);
  const f32x4 gv = *(const f32x4*)(g + lane * 4);
  bf16x4 o;
#pragma unroll
  for (int j = 0; j < 4; ++j) o[j] = (__bf16)(v[j] * scale * gv[j]);
  *(bf16x4*)(out + i) = o;
}

// single fused fp32->bf16 conversion: x first (94% of threads exit in 1 branch),
// then 7 weight segments.
struct CvtPack { const float* s[8]; __bf16* d[8]; int n[8]; };
__global__ void cvt_all_kernel(CvtPack p)
{
  int i = (blockIdx.x * 256 + threadIdx.x) * 4;
#pragma unroll
  for (int k = 0; k < 8; ++k) {
    if (i < p.n[k]) {
      const f32x4 v = *(const f32x4*)(p.s[k] + i);
      bf16x4 o;
#pragma unroll
      for (int j = 0; j < 4; ++j) o[j] = (__bf16)v[j];
      *(bf16x4*)(p.d[k] + i) = o;
      return;
    }
    i -= p.n[k];
  }
}

// Flash attention: no-max softmax (p=exp(s/8), additive partials), kv-split x2,
// balanced qb pairing, swizzled conflict-free LDS. O-partials in bf16.
// grid (16 bh, 32 ycode, 2 z), block 256 (4 waves x 16 q-rows).
__global__ __launch_bounds__(256, 4) void attn_kernel(
    const __bf16* __restrict__ qkv, __bf16* __restrict__ opart, float* __restrict__ lpart)
{
  const int bh = blockIdx.x;
  const int by = blockIdx.y;
  const int qb = (by < 16) ? (31 - by) : (by - 16);
  const int z = blockIdx.z;
  const int b = bh >> 2, hh = bh & 3;
  const int tid = threadIdx.x, wv = tid >> 6, lane = tid & 63;
  const int r16 = lane & 15, g4 = lane >> 4;
  const __bf16* base = qkv + (size_t)b * 2048 * 768;
  const int q0 = qb * 64;

  __shared__ __align__(16) __bf16 Ks[2][64 * 64];
  __shared__ __align__(16) __bf16 Vt[64 * 72];
  __shared__ __align__(16) __bf16 Ps[4][16 * 72];

  bf16x8 qf[2];
  {
    const __bf16* qrow = base + (size_t)(q0 + wv * 16 + r16) * 768 + hh * 64;
    qf[0] = *(const bf16x8*)(qrow + g4 * 8);
    qf[1] = *(const bf16x8*)(qrow + 32 + g4 * 8);
  }

  f32x4 oacc[4];
#pragma unroll
  for (int t = 0; t < 4; ++t) oacc[t] = f32x4{0.f, 0.f, 0.f, 0.f};
  float lsum[4] = {0.f, 0.f, 0.f, 0.f};

  auto stageK = [&](int buf, int kv0) {
#pragma unroll
    for (int rr = 0; rr < 2; ++rr) {
      const int u = rr * 256 + tid;
      const int kv = u >> 3, c = u & 7;
      g2lds16(&Ks[buf][u * 8],
              base + (size_t)(kv0 + kv) * 768 + 256 + hh * 64 + ((c ^ (kv & 7)) * 8));
    }
  };
  const int vrow = tid >> 2, vdg = (tid & 3) * 16;
  const int va_ = vrow >> 3, vb_ = vrow & 7;

  bf16x8 v0r, v1r;
  auto loadV = [&](int kv0) {
    const __bf16* vsrc = base + (size_t)(kv0 + vrow) * 768 + 512 + hh * 64 + vdg;
    v0r = *(const bf16x8*)vsrc;
    v1r = *(const bf16x8*)(vsrc + 8);
  };
  auto writeVt = [&]() {
#pragma unroll
    for (int i = 0; i < 8; ++i) {
      int d = vdg + i;
      Vt[d * 72 + ((va_ ^ (d >> 3)) << 3) + vb_] = v0r[i];
      d = vdg + 8 + i;
      Vt[d * 72 + ((va_ ^ (d >> 3)) << 3) + vb_] = v1r[i];
    }
  };

  int c = z, cur = 0;
  const bool any = (c <= qb);
  if (any) { stageK(0, c * 64); loadV(c * 64); }
  __syncthreads();
  if (any) writeVt();
  __syncthreads();

  while (c <= qb) {
    const int nxt = c + 2;
    if (nxt <= qb) { stageK(cur ^ 1, nxt * 64); loadV(nxt * 64); }

    f32x4 sacc[4];
#pragma unroll
    for (int t = 0; t < 4; ++t) sacc[t] = f32x4{0.f, 0.f, 0.f, 0.f};
#pragma unroll
    for (int t = 0; t < 4; ++t)
#pragma unroll
      for (int kk = 0; kk < 2; ++kk) {
        const bf16x8 kf = *(const bf16x8*)
            &Ks[cur][(t * 16 + r16) * 64 + (((kk * 4 + g4) ^ (r16 & 7)) * 8)];
        sacc[t] = MFMA_BF16(qf[kk], kf, sacc[t]);
      }

    const bool diag = (c == qb);
#pragma unroll
    for (int t = 0; t < 4; ++t)
#pragma unroll
      for (int r = 0; r < 4; ++r) {
        float p = __expf(sacc[t][r] * 0.125f);
        if (diag && (t * 16 + r16 > wv * 16 + g4 * 4 + r)) p = 0.f;
        lsum[r] += p;
        Ps[wv][(g4 * 4 + r) * 72 + t * 16 + r16] = (__bf16)p;
      }
    bf16x8 pa[2];
    pa[0] = *(const bf16x8*)&Ps[wv][r16 * 72 + g4 * 8];
    pa[1] = *(const bf16x8*)&Ps[wv][r16 * 72 + 32 + g4 * 8];

#pragma unroll
    for (int t2 = 0; t2 < 4; ++t2)
#pragma unroll
      for (int kk = 0; kk < 2; ++kk) {
        const int d = t2 * 16 + r16;
        const bf16x8 vf = *(const bf16x8*)
            &Vt[d * 72 + (((kk * 4 + g4) ^ (d >> 3)) * 8)];
        oacc[t2] = MFMA_BF16(pa[kk], vf, oacc[t2]);
      }

    __syncthreads();
    if (nxt <= qb) writeVt();
    __syncthreads();
    c = nxt;
    cur ^= 1;
  }

#pragma unroll
  for (int r = 0; r < 4; ++r) {
    lsum[r] += __shfl_xor(lsum[r], 1);
    lsum[r] += __shfl_xor(lsum[r], 2);
    lsum[r] += __shfl_xor(lsum[r], 4);
    lsum[r] += __shfl_xor(lsum[r], 8);
  }
  const size_t pb = (size_t)(bh * 32 + qb) * 2 + z;
  __bf16* op = opart + pb * 4096;
#pragma unroll
  for (int t2 = 0; t2 < 4; ++t2)
#pragma unroll
    for (int r = 0; r < 4; ++r)
      op[(wv * 16 + g4 * 4 + r) * 64 + t2 * 16 + r16] = (__bf16)oacc[t2][r];
  if (r16 == 0) {
    float* lp = lpart + pb * 64;
#pragma unroll
    for (int r = 0; r < 4; ++r) lp[wv * 16 + g4 * 4 + r] = lsum[r];
  }
}

extern "C" void kernel_launch(void* const* d_in, const int* in_sizes, int n_in,
                              void* d_out, int out_size, void* d_ws, size_t ws_size,
                              hipStream_t stream) {
  (void)in_sizes; (void)n_in; (void)out_size; (void)ws_size;
  const float* x     = (const float*)d_in[0];
  const float* Wdown = (const float*)d_in[1];
  const float* Wup   = (const float*)d_in[2];
  const float* Wqkv  = (const float*)d_in[3];
  const float* Wo    = (const float*)d_in[4];
  const float* Wgate = (const float*)d_in[5];
  const float* Wupff = (const float*)d_in[6];
  const float* Wdff  = (const float*)d_in[7];
  const float* g1    = (const float*)d_in[8];
  const float* g2    = (const float*)d_in[9];
  float* out = (float*)d_out;   // output is fp32 (verified R5)

  const size_t MB = 1 << 20;
  char* ws = (char*)d_ws;
  float*  h  = (float*)ws;                            // [0, 8M)
  __bf16* hn = (__bf16*)(ws + 8 * MB);                // [8M, 12M)
  __bf16* hb = (__bf16*)(ws + 12 * MB);               // [12M, 16M)
  __bf16* wb_down = (__bf16*)(ws + 16 * MB);
  __bf16* wb_up   = (__bf16*)(ws + 18 * MB);
  __bf16* wb_qkv  = (__bf16*)(ws + 20 * MB);
  __bf16* wb_o    = (__bf16*)(ws + 20 * MB + 384 * 1024);
  __bf16* wb_gate = (__bf16*)(ws + 20 * MB + 512 * 1024);
  __bf16* wb_upff = (__bf16*)(ws + 20 * MB + 768 * 1024);
  __bf16* wb_dff  = (__bf16*)(ws + 21 * MB);

  // d_out (128 MiB) doubles as scratch. Lifetimes (all dead before final GEMM):
  //   xb    [0,64M)    cvt -> gemm1
  //   hpart [64,80M)   gemm1 -> rmsnorm_reduce (4 x 4MB bf16)
  //   qkv   [0,12M)    qkv-gemm -> attn          (xb dead)
  //   ffmid [12,20M)   gu_rms-gemm -> dff-gemm
  //   opart [36,44.4M) attn -> wo-gemm (bf16, 2 kv-split partials)
  //   lpart [53,53.25M)
  char* ob = (char*)d_out;
  __bf16* xb    = (__bf16*)(ob);
  __bf16* hpart = (__bf16*)(ob + 64 * MB);
  __bf16* qkv   = (__bf16*)(ob);
  __bf16* ffmid = (__bf16*)(ob + 12 * MB);
  __bf16* opart = (__bf16*)(ob + 36 * MB);
  float* lpart  = (float*)(ob + 53 * MB);

  CvtPack cp;
  cp.s[0] = x;     cp.d[0] = xb;      cp.n[0] = 33554432;
  cp.s[1] = Wdown; cp.d[1] = wb_down; cp.n[1] = 1048576;
  cp.s[2] = Wup;   cp.d[2] = wb_up;   cp.n[2] = 1048576;
  cp.s[3] = Wqkv;  cp.d[3] = wb_qkv;  cp.n[3] = 196608;
  cp.s[4] = Wo;    cp.d[4] = wb_o;    cp.n[4] = 65536;
  cp.s[5] = Wgate; cp.d[5] = wb_gate; cp.n[5] = 131072;
  cp.s[6] = Wupff; cp.d[6] = wb_upff; cp.n[6] = 131072;
  cp.s[7] = Wdff;  cp.d[7] = wb_dff;  cp.n[7] = 131072;
  cvt_all_kernel<<<35456, 256, 0, stream>>>(cp);

  // h_part = xb @ Wdown^T : bf16 template, split-K x4 (512 blocks = 2/CU).
  gemm_nt_kernel<EP_BF16, 128, true><<<dim3(2, 64, 4), 256, 0, stream>>>(
      xb, wb_down, 4096, hpart, nullptr, 256);
  // h = sum 4 partials; hn = rmsnorm(h)*g1  (fused)
  rmsnorm_reduce_kernel<<<2048, 256, 0, stream>>>(hpart, g1, h, hn);

  gemm_nt_kernel<EP_BF16, 64><<<dim3(6, 128), 256, 0, stream>>>(
      hn, wb_qkv, 256, qkv, nullptr, 768);
  attn_kernel<<<dim3(16, 32, 2), 256, 0, stream>>>(qkv, opart, lpart);
  // h += merge(opart,lpart) @ Wo^T  (2-way merge fused into A-staging)
  gemm_wo_kernel<<<dim3(2, 256), 256, 0, stream>>>(opart, lpart, wb_o, h);
  // ffmid = silu(rms(h)g2 @ Wgate^T) * (rms(h)g2 @ Wupff^T)  (rmsnorm fused)
  gemm_gu_rms_kernel<<<dim3(4, 128), 256, 0, stream>>>(h, g2, wb_gate, wb_upff, ffmid);
  // h += ffmid @ Wdff^T ; hb = bf16(h)   (32-row tiles, 512 blocks)
  gemm_nt_kernel<EP_ADD_BF16OUT, 32><<<dim3(2, 256), 256, 0, stream>>>(
      ffmid, wb_dff, 512, hb, h, 256);
  // out = hb @ Wup^T  -> fp32 non-temporal stores
  gemm_nt_kernel<EP_F32, 128><<<dim3(32, 64), 256, 0, stream>>>(
      hb, wb_up, 256, nullptr, out, 4096);
}

// Round 20
// 195.034 us; speedup vs baseline: 1.0264x; 1.0071x over previous
//
#include <hip/hip_runtime.h>
#include <hip/hip_bf16.h>

typedef __bf16 bf16x8 __attribute__((ext_vector_type(8)));
typedef __bf16 bf16x4 __attribute__((ext_vector_type(4)));
typedef float f32x4 __attribute__((ext_vector_type(4)));

#define MFMA_BF16(a, b, c) __builtin_amdgcn_mfma_f32_16x16x32_bf16((a), (b), (c), 0, 0, 0)

__device__ __forceinline__ void g2lds16(void* lds, const void* g) {
  __builtin_amdgcn_global_load_lds(
      (const __attribute__((address_space(1))) void*)g,
      (__attribute__((address_space(3))) void*)lds, 16, 0, 0);
}

enum { EP_BF16 = 0, EP_F32 = 1, EP_ADD_F32 = 2, EP_ADD_BF16OUT = 3 };

// ---------------- generic bf16 GEMM (A,B bf16, g2lds staged) ----------------
// MT=128: 2x2 waves of 64x64. MT=64: 1x4 waves of 64x32. MT=32: 1x4 of 32x32.
// SPLITK: grid.z selects K-chunk [z*1024, ...); bf16 partial to Co+z*2M.
template <int EPI, int MT, bool SPLITK = false>
__global__ __launch_bounds__(256, 4) void gemm_nt_kernel(
    const __bf16* __restrict__ A, const __bf16* __restrict__ B, const int K,
    __bf16* __restrict__ Co, float* __restrict__ Cf, const int ldc)
{
  __shared__ __align__(16) __bf16 As[2][MT * 32];
  __shared__ __align__(16) __bf16 Bs[2][128 * 32];
  const int tid = threadIdx.x;
  const int wv = tid >> 6, lane = tid & 63;
  const int r16 = lane & 15, g4 = lane >> 4;
  const int row0 = blockIdx.y * MT, col0 = blockIdx.x * 128;
  const int wr = (MT == 128) ? (wv >> 1) * 64 : 0;
  const int wc = (MT == 128) ? (wv & 1) * 64 : wv * 32;
  constexpr int NW = (MT == 128) ? 4 : 2;
  constexpr int MFR = (MT >= 64) ? 4 : 2;
  const int kz0 = SPLITK ? blockIdx.z * 1024 : 0;

  f32x4 acc[MFR][NW];
#pragma unroll
  for (int m = 0; m < MFR; ++m)
#pragma unroll
    for (int n = 0; n < NW; ++n) acc[m][n] = f32x4{0.f, 0.f, 0.f, 0.f};

  auto stage = [&](int buf, int k0) {
    if constexpr (MT == 32) {
      if (tid < 128) {
        const int u = tid, row = u >> 2, cg = ((u & 3) ^ (row & 3)) * 8;
        g2lds16(&As[buf][u * 8], A + (size_t)(row0 + row) * K + k0 + cg);
      }
    } else {
#pragma unroll
      for (int rr = 0; rr < MT / 64; ++rr) {
        const int u = rr * 256 + tid, row = u >> 2, cg = ((u & 3) ^ (row & 3)) * 8;
        g2lds16(&As[buf][u * 8], A + (size_t)(row0 + row) * K + k0 + cg);
      }
    }
#pragma unroll
    for (int rr = 0; rr < 2; ++rr) {
      const int u = rr * 256 + tid, row = u >> 2, cg = ((u & 3) ^ (row & 3)) * 8;
      g2lds16(&Bs[buf][u * 8], B + (size_t)(col0 + row) * K + k0 + cg);
    }
  };

  const int nk = SPLITK ? 32 : (K >> 5);
  const int csw = (g4 ^ (r16 & 3)) * 8;
  int cur = 0;
  stage(0, kz0);
  __syncthreads();

  for (int t = 0; t < nk; ++t) {
    if (t + 1 < nk) stage(cur ^ 1, kz0 + (t + 1) * 32);
    bf16x8 af[MFR], bfr[NW];
#pragma unroll
    for (int m = 0; m < MFR; ++m)
      af[m] = *(const bf16x8*)&As[cur][(wr + m * 16 + r16) * 32 + csw];
#pragma unroll
    for (int n = 0; n < NW; ++n)
      bfr[n] = *(const bf16x8*)&Bs[cur][(wc + n * 16 + r16) * 32 + csw];
#pragma unroll
    for (int m = 0; m < MFR; ++m)
#pragma unroll
      for (int n = 0; n < NW; ++n)
        acc[m][n] = MFMA_BF16(af[m], bfr[n], acc[m][n]);
    __syncthreads();
    cur ^= 1;
  }

  const size_t zoff = SPLITK ? (size_t)blockIdx.z * 2097152 : 0;
  // C/D layout: col = lane&15, row = (lane>>4)*4 + reg
#pragma unroll
  for (int m = 0; m < MFR; ++m)
#pragma unroll
    for (int n = 0; n < NW; ++n)
#pragma unroll
      for (int r = 0; r < 4; ++r) {
        const int row = row0 + wr + m * 16 + g4 * 4 + r;
        const int col = col0 + wc + n * 16 + r16;
        const size_t idx = (size_t)row * ldc + col;
        const float v = acc[m][n][r];
        if constexpr (EPI == EP_BF16) Co[zoff + idx] = (__bf16)v;
        else if constexpr (EPI == EP_F32) Cf[idx] = v;   // plain store (A/B vs NT)
        else if constexpr (EPI == EP_ADD_F32) Cf[idx] += v;
        else Co[idx] = (__bf16)(Cf[idx] + v);
      }
}

// ---- fused rmsnorm2 + gate/up GEMM + silu*mul ----
// ffmid = silu(rms(h)g2 @ Wg^T) * (rms(h)g2 @ Wu^T).  grid (4,128), block 256.
__global__ __launch_bounds__(256, 2) void gemm_gu_rms_kernel(
    const float* __restrict__ h, const float* __restrict__ g2,
    const __bf16* __restrict__ Bg, const __bf16* __restrict__ Bu,
    __bf16* __restrict__ ffmid)
{
  __shared__ __align__(16) __bf16 As[64 * 256];      // 32 KB, resident
  __shared__ __align__(16) __bf16 Bgs[2][128 * 32];
  __shared__ __align__(16) __bf16 Bus[2][128 * 32];
  const int tid = threadIdx.x;
  const int wv = tid >> 6, lane = tid & 63;
  const int r16 = lane & 15, g4 = lane >> 4;
  const int row0 = blockIdx.y * 64, col0 = blockIdx.x * 128;
  const int wc = wv * 32;

  auto stageB = [&](int buf, int k0) {
#pragma unroll
    for (int rr = 0; rr < 2; ++rr) {
      const int u = rr * 256 + tid, row = u >> 2, cg = ((u & 3) ^ (row & 3)) * 8;
      g2lds16(&Bgs[buf][u * 8], Bg + (size_t)(col0 + row) * 256 + k0 + cg);
      g2lds16(&Bus[buf][u * 8], Bu + (size_t)(col0 + row) * 256 + k0 + cg);
    }
  };

  stageB(0, 0);   // overlap B-staging with phase 1

  // Phase 1: rmsnorm rows of h into As.
  {
    const int r = tid >> 2, q = tid & 3;            // row 0..63, col-quarter
    const float* hrow = h + (size_t)(row0 + r) * 256 + q * 64;
    f32x4 hv[16];
    float s = 0.f;
#pragma unroll
    for (int j = 0; j < 16; ++j) {
      hv[j] = *(const f32x4*)(hrow + j * 4);
      s += hv[j][0]*hv[j][0] + hv[j][1]*hv[j][1] + hv[j][2]*hv[j][2] + hv[j][3]*hv[j][3];
    }
    s += __shfl_xor(s, 1);
    s += __shfl_xor(s, 2);
    const float scale = rsqrtf(s * (1.f / 256.f) + 1.1920929e-07f);
#pragma unroll
    for (int cj = 0; cj < 8; ++cj) {
      const int cc = q * 8 + cj;
      const int ccs = cc ^ (r & 15);
      const f32x4 ga = *(const f32x4*)(g2 + q * 64 + cj * 8);
      const f32x4 gb = *(const f32x4*)(g2 + q * 64 + cj * 8 + 4);
      bf16x8 w;
#pragma unroll
      for (int e = 0; e < 4; ++e) {
        w[e]     = (__bf16)(hv[cj * 2][e] * scale * ga[e]);
        w[4 + e] = (__bf16)(hv[cj * 2 + 1][e] * scale * gb[e]);
      }
      *(bf16x8*)&As[r * 256 + ccs * 8] = w;
    }
  }
  __syncthreads();

  f32x4 accG[4][2], accU[4][2];
#pragma unroll
  for (int m = 0; m < 4; ++m)
#pragma unroll
    for (int n = 0; n < 2; ++n) {
      accG[m][n] = f32x4{0.f, 0.f, 0.f, 0.f};
      accU[m][n] = f32x4{0.f, 0.f, 0.f, 0.f};
    }

  const int csw = (g4 ^ (r16 & 3)) * 8;
  int cur = 0;
  for (int t = 0; t < 8; ++t) {
    if (t + 1 < 8) stageB(cur ^ 1, (t + 1) * 32);
    bf16x8 af[4], bg[2], bu[2];
#pragma unroll
    for (int m = 0; m < 4; ++m) {
      const int row = m * 16 + r16;
      const int ccs = (t * 4 + g4) ^ r16;
      af[m] = *(const bf16x8*)&As[row * 256 + ccs * 8];
    }
#pragma unroll
    for (int n = 0; n < 2; ++n) {
      bg[n] = *(const bf16x8*)&Bgs[cur][(wc + n * 16 + r16) * 32 + csw];
      bu[n] = *(const bf16x8*)&Bus[cur][(wc + n * 16 + r16) * 32 + csw];
    }
#pragma unroll
    for (int m = 0; m < 4; ++m)
#pragma unroll
      for (int n = 0; n < 2; ++n) {
        accG[m][n] = MFMA_BF16(af[m], bg[n], accG[m][n]);
        accU[m][n] = MFMA_BF16(af[m], bu[n], accU[m][n]);
      }
    __syncthreads();
    cur ^= 1;
  }

#pragma unroll
  for (int m = 0; m < 4; ++m)
#pragma unroll
    for (int n = 0; n < 2; ++n)
#pragma unroll
      for (int r = 0; r < 4; ++r) {
        const int row = row0 + m * 16 + g4 * 4 + r;
        const int col = col0 + wc + n * 16 + r16;
        const float g = accG[m][n][r];
        const float u = accU[m][n][r];
        ffmid[(size_t)row * 512 + col] = (__bf16)((g / (1.f + __expf(-g))) * u);
      }
}

// ---- Wo GEMM with fused attn-merge A-staging: h += merge(opart) @ Wo^T ----
// grid (2, 256): 32-row x 128-col tiles, K=256 (8 iters: t -> hh=t>>1, half=t&1).
// Merge sums 2 kv-split partials in fixed order (deterministic).
__global__ __launch_bounds__(256, 2) void gemm_wo_kernel(
    const __bf16* __restrict__ opart, const float* __restrict__ lpart,
    const __bf16* __restrict__ B, float* __restrict__ Cf)
{
  __shared__ __align__(16) __bf16 As[2][32 * 32];
  __shared__ __align__(16) __bf16 Bs[2][128 * 32];
  const int tid = threadIdx.x;
  const int wv = tid >> 6, lane = tid & 63;
  const int r16 = lane & 15, g4 = lane >> 4;
  const int row0 = blockIdx.y * 32, col0 = blockIdx.x * 128;
  const int wc = wv * 32;

  f32x4 acc[2][2];
#pragma unroll
  for (int m = 0; m < 2; ++m)
#pragma unroll
    for (int n = 0; n < 2; ++n) acc[m][n] = f32x4{0.f, 0.f, 0.f, 0.f};

  const int arow = tid >> 2;
  const int R = row0 + (arow & 31);
  const int b = R >> 11, rr_ = R & 2047;
  const int qb = rr_ >> 6, rloc = rr_ & 63;
  const int cgrp = ((tid & 3) ^ (arow & 3)) * 8;

  auto stageA = [&](int buf, int t) {
    if (tid < 128) {
      const int hh = t >> 1;
      const int dbase = (t & 1) * 32 + cgrp;
      const size_t pb = ((size_t)((b * 4 + hh) * 32 + qb)) * 2;
      const bf16x8 o0 = *(const bf16x8*)(opart + pb * 4096 + rloc * 64 + dbase);
      const bf16x8 o1 = *(const bf16x8*)(opart + (pb + 1) * 4096 + rloc * 64 + dbase);
      const float inv = 1.f / (lpart[pb * 64 + rloc] + lpart[(pb + 1) * 64 + rloc]);
      bf16x8 w;
#pragma unroll
      for (int j = 0; j < 8; ++j) w[j] = (__bf16)(((float)o0[j] + (float)o1[j]) * inv);
      *(bf16x8*)&As[buf][tid * 8] = w;
    }
  };
  auto stageB = [&](int buf, int k0) {
#pragma unroll
    for (int rr = 0; rr < 2; ++rr) {
      const int u = rr * 256 + tid, row = u >> 2, cg = ((u & 3) ^ (row & 3)) * 8;
      g2lds16(&Bs[buf][u * 8], B + (size_t)(col0 + row) * 256 + k0 + cg);
    }
  };

  const int csw = (g4 ^ (r16 & 3)) * 8;
  int cur = 0;
  stageA(0, 0);
  stageB(0, 0);
  __syncthreads();

  for (int t = 0; t < 8; ++t) {
    if (t + 1 < 8) { stageA(cur ^ 1, t + 1); stageB(cur ^ 1, (t + 1) * 32); }
    bf16x8 af[2], bfr[2];
#pragma unroll
    for (int m = 0; m < 2; ++m)
      af[m] = *(const bf16x8*)&As[cur][(m * 16 + r16) * 32 + csw];
#pragma unroll
    for (int n = 0; n < 2; ++n)
      bfr[n] = *(const bf16x8*)&Bs[cur][(wc + n * 16 + r16) * 32 + csw];
#pragma unroll
    for (int m = 0; m < 2; ++m)
#pragma unroll
      for (int n = 0; n < 2; ++n)
        acc[m][n] = MFMA_BF16(af[m], bfr[n], acc[m][n]);
    __syncthreads();
    cur ^= 1;
  }

#pragma unroll
  for (int m = 0; m < 2; ++m)
#pragma unroll
    for (int n = 0; n < 2; ++n)
#pragma unroll
      for (int r = 0; r < 4; ++r) {
        const int row = row0 + m * 16 + g4 * 4 + r;
        const int col = col0 + wc + n * 16 + r16;
        Cf[(size_t)row * 256 + col] += acc[m][n][r];
      }
}

// fused: h = sum_z bf16 part[z] (4 partials); hn = rmsnorm(h)*g.
__global__ void rmsnorm_reduce_kernel(const __bf16* __restrict__ part, const float* __restrict__ g,
                                      float* __restrict__ h, __bf16* __restrict__ out)
{
  const int wv = threadIdx.x >> 6, lane = threadIdx.x & 63;
  const size_t row = (size_t)blockIdx.x * 4 + wv;
  const size_t i = row * 256 + lane * 4;
  f32x4 v = {0.f, 0.f, 0.f, 0.f};
#pragma unroll
  for (int z = 0; z < 4; ++z) {
    const bf16x4 p = *(const bf16x4*)(part + (size_t)z * 2097152 + i);
#pragma unroll
    for (int j = 0; j < 4; ++j) v[j] += (float)p[j];
  }
  *(f32x4*)(h + i) = v;
  float s = v[0] * v[0] + v[1] * v[1] + v[2] * v[2] + v[3] * v[3];
#pragma unroll
  for (int off = 1; off < 64; off <<= 1) s += __shfl_xor(s, off);
  const float scale = rsqrtf(s * (1.f / 256.f) + 1.1920929e-07f);
  const f32x4 gv = *(const f32x4*)(g + lane * 4);
  bf16x4 o;
#pragma unroll
  for (int j = 0; j < 4; ++j) o[j] = (__bf16)(v[j] * scale * gv[j]);
  *(bf16x4*)(out + i) = o;
}

// single fused fp32->bf16 conversion: x first (94% of threads exit in 1 branch),
// then 7 weight segments.
struct CvtPack { const float* s[8]; __bf16* d[8]; int n[8]; };
__global__ void cvt_all_kernel(CvtPack p)
{
  int i = (blockIdx.x * 256 + threadIdx.x) * 4;
#pragma unroll
  for (int k = 0; k < 8; ++k) {
    if (i < p.n[k]) {
      const f32x4 v = *(const f32x4*)(p.s[k] + i);
      bf16x4 o;
#pragma unroll
      for (int j = 0; j < 4; ++j) o[j] = (__bf16)v[j];
      *(bf16x4*)(p.d[k] + i) = o;
      return;
    }
    i -= p.n[k];
  }
}

// Flash attention: no-max softmax (p=exp(s/8), additive partials), kv-split x2,
// balanced qb pairing, swizzled conflict-free LDS. O-partials in bf16.
// grid (16 bh, 32 ycode, 2 z), block 256 (4 waves x 16 q-rows).
__global__ __launch_bounds__(256, 4) void attn_kernel(
    const __bf16* __restrict__ qkv, __bf16* __restrict__ opart, float* __restrict__ lpart)
{
  const int bh = blockIdx.x;
  const int by = blockIdx.y;
  const int qb = (by < 16) ? (31 - by) : (by - 16);
  const int z = blockIdx.z;
  const int b = bh >> 2, hh = bh & 3;
  const int tid = threadIdx.x, wv = tid >> 6, lane = tid & 63;
  const int r16 = lane & 15, g4 = lane >> 4;
  const __bf16* base = qkv + (size_t)b * 2048 * 768;
  const int q0 = qb * 64;

  __shared__ __align__(16) __bf16 Ks[2][64 * 64];
  __shared__ __align__(16) __bf16 Vt[64 * 72];
  __shared__ __align__(16) __bf16 Ps[4][16 * 72];

  bf16x8 qf[2];
  {
    const __bf16* qrow = base + (size_t)(q0 + wv * 16 + r16) * 768 + hh * 64;
    qf[0] = *(const bf16x8*)(qrow + g4 * 8);
    qf[1] = *(const bf16x8*)(qrow + 32 + g4 * 8);
  }

  f32x4 oacc[4];
#pragma unroll
  for (int t = 0; t < 4; ++t) oacc[t] = f32x4{0.f, 0.f, 0.f, 0.f};
  float lsum[4] = {0.f, 0.f, 0.f, 0.f};

  auto stageK = [&](int buf, int kv0) {
#pragma unroll
    for (int rr = 0; rr < 2; ++rr) {
      const int u = rr * 256 + tid;
      const int kv = u >> 3, c = u & 7;
      g2lds16(&Ks[buf][u * 8],
              base + (size_t)(kv0 + kv) * 768 + 256 + hh * 64 + ((c ^ (kv & 7)) * 8));
    }
  };
  const int vrow = tid >> 2, vdg = (tid & 3) * 16;
  const int va_ = vrow >> 3, vb_ = vrow & 7;

  bf16x8 v0r, v1r;
  auto loadV = [&](int kv0) {
    const __bf16* vsrc = base + (size_t)(kv0 + vrow) * 768 + 512 + hh * 64 + vdg;
    v0r = *(const bf16x8*)vsrc;
    v1r = *(const bf16x8*)(vsrc + 8);
  };
  auto writeVt = [&]() {
#pragma unroll
    for (int i = 0; i < 8; ++i) {
      int d = vdg + i;
      Vt[d * 72 + ((va_ ^ (d >> 3)) << 3) + vb_] = v0r[i];
      d = vdg + 8 + i;
      Vt[d * 72 + ((va_ ^ (d >> 3)) << 3) + vb_] = v1r[i];
    }
  };

  int c = z, cur = 0;
  const bool any = (c <= qb);
  if (any) { stageK(0, c * 64); loadV(c * 64); }
  __syncthreads();
  if (any) writeVt();
  __syncthreads();

  while (c <= qb) {
    const int nxt = c + 2;
    if (nxt <= qb) { stageK(cur ^ 1, nxt * 64); loadV(nxt * 64); }

    f32x4 sacc[4];
#pragma unroll
    for (int t = 0; t < 4; ++t) sacc[t] = f32x4{0.f, 0.f, 0.f, 0.f};
#pragma unroll
    for (int t = 0; t < 4; ++t)
#pragma unroll
      for (int kk = 0; kk < 2; ++kk) {
        const bf16x8 kf = *(const bf16x8*)
            &Ks[cur][(t * 16 + r16) * 64 + (((kk * 4 + g4) ^ (r16 & 7)) * 8)];
        sacc[t] = MFMA_BF16(qf[kk], kf, sacc[t]);
      }

    const bool diag = (c == qb);
#pragma unroll
    for (int t = 0; t < 4; ++t)
#pragma unroll
      for (int r = 0; r < 4; ++r) {
        float p = __expf(sacc[t][r] * 0.125f);
        if (diag && (t * 16 + r16 > wv * 16 + g4 * 4 + r)) p = 0.f;
        lsum[r] += p;
        Ps[wv][(g4 * 4 + r) * 72 + t * 16 + r16] = (__bf16)p;
      }
    bf16x8 pa[2];
    pa[0] = *(const bf16x8*)&Ps[wv][r16 * 72 + g4 * 8];
    pa[1] = *(const bf16x8*)&Ps[wv][r16 * 72 + 32 + g4 * 8];

#pragma unroll
    for (int t2 = 0; t2 < 4; ++t2)
#pragma unroll
      for (int kk = 0; kk < 2; ++kk) {
        const int d = t2 * 16 + r16;
        const bf16x8 vf = *(const bf16x8*)
            &Vt[d * 72 + (((kk * 4 + g4) ^ (d >> 3)) * 8)];
        oacc[t2] = MFMA_BF16(pa[kk], vf, oacc[t2]);
      }

    __syncthreads();
    if (nxt <= qb) writeVt();
    __syncthreads();
    c = nxt;
    cur ^= 1;
  }

#pragma unroll
  for (int r = 0; r < 4; ++r) {
    lsum[r] += __shfl_xor(lsum[r], 1);
    lsum[r] += __shfl_xor(lsum[r], 2);
    lsum[r] += __shfl_xor(lsum[r], 4);
    lsum[r] += __shfl_xor(lsum[r], 8);
  }
  const size_t pb = (size_t)(bh * 32 + qb) * 2 + z;
  __bf16* op = opart + pb * 4096;
#pragma unroll
  for (int t2 = 0; t2 < 4; ++t2)
#pragma unroll
    for (int r = 0; r < 4; ++r)
      op[(wv * 16 + g4 * 4 + r) * 64 + t2 * 16 + r16] = (__bf16)oacc[t2][r];
  if (r16 == 0) {
    float* lp = lpart + pb * 64;
#pragma unroll
    for (int r = 0; r < 4; ++r) lp[wv * 16 + g4 * 4 + r] = lsum[r];
  }
}

extern "C" void kernel_launch(void* const* d_in, const int* in_sizes, int n_in,
                              void* d_out, int out_size, void* d_ws, size_t ws_size,
                              hipStream_t stream) {
  (void)in_sizes; (void)n_in; (void)out_size; (void)ws_size;
  const float* x     = (const float*)d_in[0];
  const float* Wdown = (const float*)d_in[1];
  const float* Wup   = (const float*)d_in[2];
  const float* Wqkv  = (const float*)d_in[3];
  const float* Wo    = (const float*)d_in[4];
  const float* Wgate = (const float*)d_in[5];
  const float* Wupff = (const float*)d_in[6];
  const float* Wdff  = (const float*)d_in[7];
  const float* g1    = (const float*)d_in[8];
  const float* g2    = (const float*)d_in[9];
  float* out = (float*)d_out;   // output is fp32 (verified R5)

  const size_t MB = 1 << 20;
  char* ws = (char*)d_ws;
  float*  h  = (float*)ws;                            // [0, 8M)
  __bf16* hn = (__bf16*)(ws + 8 * MB);                // [8M, 12M)
  __bf16* hb = (__bf16*)(ws + 12 * MB);               // [12M, 16M)
  __bf16* wb_down = (__bf16*)(ws + 16 * MB);
  __bf16* wb_up   = (__bf16*)(ws + 18 * MB);
  __bf16* wb_qkv  = (__bf16*)(ws + 20 * MB);
  __bf16* wb_o    = (__bf16*)(ws + 20 * MB + 384 * 1024);
  __bf16* wb_gate = (__bf16*)(ws + 20 * MB + 512 * 1024);
  __bf16* wb_upff = (__bf16*)(ws + 20 * MB + 768 * 1024);
  __bf16* wb_dff  = (__bf16*)(ws + 21 * MB);

  // d_out (128 MiB) doubles as scratch. Lifetimes (all dead before final GEMM):
  //   xb    [0,64M)    cvt -> gemm1
  //   hpart [64,80M)   gemm1 -> rmsnorm_reduce (4 x 4MB bf16)
  //   qkv   [0,12M)    qkv-gemm -> attn          (xb dead)
  //   ffmid [12,20M)   gu_rms-gemm -> dff-gemm
  //   opart [36,44.4M) attn -> wo-gemm (bf16, 2 kv-split partials)
  //   lpart [53,53.25M)
  char* ob = (char*)d_out;
  __bf16* xb    = (__bf16*)(ob);
  __bf16* hpart = (__bf16*)(ob + 64 * MB);
  __bf16* qkv   = (__bf16*)(ob);
  __bf16* ffmid = (__bf16*)(ob + 12 * MB);
  __bf16* opart = (__bf16*)(ob + 36 * MB);
  float* lpart  = (float*)(ob + 53 * MB);

  CvtPack cp;
  cp.s[0] = x;     cp.d[0] = xb;      cp.n[0] = 33554432;
  cp.s[1] = Wdown; cp.d[1] = wb_down; cp.n[1] = 1048576;
  cp.s[2] = Wup;   cp.d[2] = wb_up;   cp.n[2] = 1048576;
  cp.s[3] = Wqkv;  cp.d[3] = wb_qkv;  cp.n[3] = 196608;
  cp.s[4] = Wo;    cp.d[4] = wb_o;    cp.n[4] = 65536;
  cp.s[5] = Wgate; cp.d[5] = wb_gate; cp.n[5] = 131072;
  cp.s[6] = Wupff; cp.d[6] = wb_upff; cp.n[6] = 131072;
  cp.s[7] = Wdff;  cp.d[7] = wb_dff;  cp.n[7] = 131072;
  cvt_all_kernel<<<35456, 256, 0, stream>>>(cp);

  // h_part = xb @ Wdown^T : bf16 template, split-K x4 (512 blocks = 2/CU).
  gemm_nt_kernel<EP_BF16, 128, true><<<dim3(2, 64, 4), 256, 0, stream>>>(
      xb, wb_down, 4096, hpart, nullptr, 256);
  // h = sum 4 partials; hn = rmsnorm(h)*g1  (fused)
  rmsnorm_reduce_kernel<<<2048, 256, 0, stream>>>(hpart, g1, h, hn);

  gemm_nt_kernel<EP_BF16, 64><<<dim3(6, 128), 256, 0, stream>>>(
      hn, wb_qkv, 256, qkv, nullptr, 768);
  attn_kernel<<<dim3(16, 32, 2), 256, 0, stream>>>(qkv, opart, lpart);
  // h += merge(opart,lpart) @ Wo^T  (2-way merge fused into A-staging)
  gemm_wo_kernel<<<dim3(2, 256), 256, 0, stream>>>(opart, lpart, wb_o, h);
  // ffmid = silu(rms(h)g2 @ Wgate^T) * (rms(h)g2 @ Wupff^T)  (rmsnorm fused)
  gemm_gu_rms_kernel<<<dim3(4, 128), 256, 0, stream>>>(h, g2, wb_gate, wb_upff, ffmid);
  // h += ffmid @ Wdff^T ; hb = bf16(h)   (32-row tiles, 512 blocks)
  gemm_nt_kernel<EP_ADD_BF16OUT, 32><<<dim3(2, 256), 256, 0, stream>>>(
      ffmid, wb_dff, 512, hb, h, 256);
  // out = hb @ Wup^T  -> fp32 plain stores (A/B: NT removed)
  gemm_nt_kernel<EP_F32, 128><<<dim3(32, 64), 256, 0, stream>>>(
      hb, wb_up, 256, nullptr, out, 4096);
}